// Round 1
// baseline (15067.842 us; speedup 1.0000x reference)
//
#include <hip/hip_runtime.h>
#include <cmath>

#define B_ 8
#define Q_ 100
#define D_ 256
#define H_ 8
#define HD_ 32
#define L_ 9
#define F_ 2048
#define C_ 151
#define HM_ 112
#define PMAX_ 3136

// ---------------- block reductions (256 threads) ----------------
__device__ __forceinline__ float block_sum(float v, float* red) {
  int t = threadIdx.x;
  red[t] = v; __syncthreads();
  for (int s = 128; s > 0; s >>= 1) {
    if (t < s) red[t] += red[t + s];
    __syncthreads();
  }
  float r = red[0]; __syncthreads();
  return r;
}

__device__ __forceinline__ float block_max(float v, float* red) {
  int t = threadIdx.x;
  red[t] = v; __syncthreads();
  for (int s = 128; s > 0; s >>= 1) {
    if (t < s) red[t] = fmaxf(red[t], red[t + s]);
    __syncthreads();
  }
  float r = red[0]; __syncthreads();
  return r;
}

// ---------------- init q = qf + qe broadcast over batch ----------------
__global__ __launch_bounds__(256) void initq_kernel(const float* __restrict__ qf,
                                                    const float* __restrict__ qe,
                                                    float* __restrict__ q) {
  int idx = blockIdx.x * 256 + threadIdx.x;     // 800*256 total
  int qd = idx % (Q_ * D_);
  q[idx] = qf[qd] + qe[qd];
}

// ---------------- generic fp32 GEMM: C = A@W (+bias)(+relu) ----------------
// A: [M,K] row-major (AT=false) or stored [K,M] (AT=true, i.e. A^T layout)
// W: [K,N] row-major. Batched via blockIdx.z with element strides Abs/Wbs/Cbs.
template <bool AT, bool RELU>
__global__ __launch_bounds__(256) void gemm_kernel(
    const float* __restrict__ A, const float* __restrict__ W,
    const float* __restrict__ bias, float* __restrict__ C,
    int M, int N, int K, long long Abs, long long Wbs, long long Cbs) {
  __shared__ float As[16][65];
  __shared__ float Ws[16][65];
  const int z = blockIdx.z;
  const float* Ab = A + (size_t)z * Abs;
  const float* Wb = W + (size_t)z * Wbs;
  float* Cb = C + (size_t)z * Cbs;
  const int n0 = blockIdx.x * 64, m0 = blockIdx.y * 64;
  const int t = threadIdx.x;
  const int tm = t >> 4, tn = t & 15;
  float acc[4][4] = {};
  for (int k0 = 0; k0 < K; k0 += 16) {
#pragma unroll
    for (int l = 0; l < 4; ++l) {
      int idx = t + l * 256;
      if (AT) {
        int ak = idx >> 6, am = idx & 63;
        int gm = m0 + am, gk = k0 + ak;
        As[ak][am] = (gm < M) ? Ab[(size_t)gk * M + gm] : 0.f;
      } else {
        int am = idx >> 4, ak = idx & 15;
        int gm = m0 + am, gk = k0 + ak;
        As[ak][am] = (gm < M) ? Ab[(size_t)gm * K + gk] : 0.f;
      }
      int wk = idx >> 6, wn = idx & 63;
      int gn = n0 + wn, gk2 = k0 + wk;
      Ws[wk][wn] = (gn < N) ? Wb[(size_t)gk2 * N + gn] : 0.f;
    }
    __syncthreads();
#pragma unroll
    for (int kk = 0; kk < 16; ++kk) {
      float a[4], b[4];
#pragma unroll
      for (int i = 0; i < 4; ++i) a[i] = As[kk][tm * 4 + i];
#pragma unroll
      for (int j = 0; j < 4; ++j) b[j] = Ws[kk][tn * 4 + j];
#pragma unroll
      for (int i = 0; i < 4; ++i)
#pragma unroll
        for (int j = 0; j < 4; ++j) acc[i][j] += a[i] * b[j];
    }
    __syncthreads();
  }
#pragma unroll
  for (int i = 0; i < 4; ++i) {
    int gm = m0 + tm * 4 + i;
    if (gm >= M) continue;
#pragma unroll
    for (int j = 0; j < 4; ++j) {
      int gn = n0 + tn * 4 + j;
      if (gn >= N) continue;
      float v = acc[i][j] + (bias ? bias[gn] : 0.f);
      if (RELU) v = fmaxf(v, 0.f);
      Cb[(size_t)gm * N + gn] = v;
    }
  }
}

// ---------------- fused residual + layernorm (block = one row, 256 = D) ----------------
template <bool RES>
__global__ __launch_bounds__(256) void ln_kernel(const float* __restrict__ x,
                                                 const float* __restrict__ r,
                                                 const float* __restrict__ s,
                                                 const float* __restrict__ b,
                                                 float* __restrict__ out) {
  __shared__ float red[256];
  size_t row = blockIdx.x;
  int t = threadIdx.x;
  float v = x[row * D_ + t];
  if (RES) v += r[row * D_ + t];
  float mean = block_sum(v, red) * (1.f / D_);
  float c = v - mean;
  float var = block_sum(c * c, red) * (1.f / D_);
  out[row * D_ + t] = c * rsqrtf(var + 1e-5f) * s[t] + b[t];
}

// ---------------- fused attention: block = (b, h, 4 query rows) ----------------
// scores row kept in LDS; softmax in LDS; PV with 2-way k-split over 256 threads.
__global__ __launch_bounds__(256) void attn_kernel(
    const float* __restrict__ qh, const float* __restrict__ kh,
    const float* __restrict__ vh, const float* __restrict__ bias,
    float* __restrict__ out, int P) {
  extern __shared__ float smem[];        // [4*P] scores + [4*32] q rows
  __shared__ float red[256];
  float* sc = smem;
  float* qs = smem + 4 * P;
  const int b = blockIdx.z, h = blockIdx.y;
  const int q0 = blockIdx.x * 4;
  const int nr = (Q_ - q0 < 4) ? (Q_ - q0) : 4;
  const int t = threadIdx.x;
  for (int idx = t; idx < nr * HD_; idx += 256) {
    int r = idx >> 5, e = idx & 31;
    qs[idx] = qh[((size_t)(b * Q_ + q0 + r)) * D_ + h * HD_ + e];
  }
  __syncthreads();
  const float scale = 0.17677669529663687f;   // 1/sqrt(32)
  for (int r = 0; r < nr; ++r) {
    const float4* qr4 = reinterpret_cast<const float4*>(qs + r * HD_);
    float4 qv[8];
#pragma unroll
    for (int e = 0; e < 8; ++e) qv[e] = qr4[e];
    const float* bp = bias ? (bias + ((size_t)(b * Q_ + q0 + r)) * P) : nullptr;
    for (int k = t; k < P; k += 256) {
      const float4* kp4 =
          reinterpret_cast<const float4*>(kh + ((size_t)(b * P + k)) * D_ + h * HD_);
      float d = 0.f;
#pragma unroll
      for (int e = 0; e < 8; ++e) {
        float4 kv = kp4[e];
        d += qv[e].x * kv.x + qv[e].y * kv.y + qv[e].z * kv.z + qv[e].w * kv.w;
      }
      d *= scale;
      if (bp) d += bp[k];
      sc[r * P + k] = d;
    }
  }
  __syncthreads();
  for (int r = 0; r < nr; ++r) {
    float m = -3.0e38f;
    for (int k = t; k < P; k += 256) m = fmaxf(m, sc[r * P + k]);
    m = block_max(m, red);
    float ssum = 0.f;
    for (int k = t; k < P; k += 256) {
      float e = expf(sc[r * P + k] - m);
      sc[r * P + k] = e;
      ssum += e;
    }
    ssum = block_sum(ssum, red);
    float inv = 1.f / ssum;
    for (int k = t; k < P; k += 256) sc[r * P + k] *= inv;
  }
  __syncthreads();
  // PV: 256 threads = 2 halves x (4 rows x 32 dims)
  const int half = t >> 7;
  const int r = (t >> 5) & 3;
  const int e = t & 31;
  float a0 = 0.f, a1 = 0.f;
  if (r < nr) {
    const float* vp = vh + ((size_t)b * P) * D_ + h * HD_ + e;
    const float* scr = sc + r * P;
    for (int k = half; k < P; k += 4) {
      a0 += scr[k] * vp[(size_t)k * D_];
      if (k + 2 < P) a1 += scr[k + 2] * vp[(size_t)(k + 2) * D_];
    }
  }
  red[t] = a0 + a1;
  __syncthreads();
  if (half == 0 && r < nr) {
    out[((size_t)(b * Q_ + q0 + r)) * D_ + h * HD_ + e] = red[t] + red[t + 128];
  }
}

// ---------------- attention-bias from prev mask ----------------
// jax.image.resize bilinear, antialias=True (tent kernel scaled by ratio),
// per-output weight normalization with edge clipping. ignore = r < 0
// (== sigmoid(r) < 0.5); fully-masked rows get un-masked.
__global__ __launch_bounds__(256) void maskbias_kernel(
    const float* __restrict__ prev,   // [B*Q, 112*112]
    float* __restrict__ bias,         // [B*Q, P]
    int oh) {                         // 14 / 28 / 56
  __shared__ float pm[HM_ * HM_];
  __shared__ float rbuf[PMAX_];
  __shared__ float red[256];
  const int row = blockIdx.x;         // b*Q + q
  const int t = threadIdx.x;
  const float* src = prev + (size_t)row * (HM_ * HM_);
  for (int i = t; i < HM_ * HM_; i += 256) pm[i] = src[i];
  __syncthreads();
  const int ratio = HM_ / oh;         // 8, 4, 2
  const int taps = 2 * ratio;
  const float invr = 1.f / (float)ratio;
  const int P = oh * oh;
  float nign = 0.f;                   // count of not-ignored
  for (int p = t; p < P; p += 256) {
    int oy = p / oh, ox = p - oy * oh;
    float sy = (oy + 0.5f) * ratio - 0.5f;
    float sx = (ox + 0.5f) * ratio - 0.5f;
    int y0 = (int)floorf(sy - ratio) + 1;
    int x0 = (int)floorf(sx - ratio) + 1;
    float wxs = 0.f;
    for (int si = 0; si < taps; ++si) {
      int x = x0 + si;
      if (x < 0 || x >= HM_) continue;
      wxs += 1.f - fabsf(sx - x) * invr;
    }
    float acc = 0.f, wys = 0.f;
    for (int ti = 0; ti < taps; ++ti) {
      int y = y0 + ti;
      if (y < 0 || y >= HM_) continue;
      float wy = 1.f - fabsf(sy - y) * invr;
      wys += wy;
      float ra = 0.f;
      const float* pr = pm + y * HM_;
      for (int si = 0; si < taps; ++si) {
        int x = x0 + si;
        if (x < 0 || x >= HM_) continue;
        float wx = 1.f - fabsf(sx - x) * invr;
        ra += wx * pr[x];
      }
      acc += wy * ra;
    }
    float rv = acc / (wys * wxs);
    rbuf[p] = rv;
    if (!(rv < 0.f)) nign += 1.f;
  }
  float tot = block_sum(nign, red);
  bool fully = (tot == 0.f);
  float* dst = bias + (size_t)row * P;
  for (int p = t; p < P; p += 256) {
    dst[p] = (!fully && rbuf[p] < 0.f) ? -1e9f : 0.f;
  }
}

// ---------------- host-side GEMM dispatch ----------------
static inline void gemm(hipStream_t st, const float* A, const float* W, const float* bias,
                        float* C, int M, int N, int K, int Z,
                        long long Abs, long long Wbs, long long Cbs, bool AT, bool relu) {
  dim3 g((N + 63) / 64, (M + 63) / 64, Z);
  if (!AT && !relu)
    gemm_kernel<false, false><<<g, 256, 0, st>>>(A, W, bias, C, M, N, K, Abs, Wbs, Cbs);
  else if (!AT && relu)
    gemm_kernel<false, true><<<g, 256, 0, st>>>(A, W, bias, C, M, N, K, Abs, Wbs, Cbs);
  else if (AT && !relu)
    gemm_kernel<true, false><<<g, 256, 0, st>>>(A, W, bias, C, M, N, K, Abs, Wbs, Cbs);
  else
    gemm_kernel<true, true><<<g, 256, 0, st>>>(A, W, bias, C, M, N, K, Abs, Wbs, Cbs);
}

extern "C" void kernel_launch(void* const* d_in, const int* in_sizes, int n_in,
                              void* d_out, int out_size, void* d_ws, size_t ws_size,
                              hipStream_t stream) {
  const float* mask_features = (const float*)d_in[0];
  const float* mem[3] = {(const float*)d_in[1], (const float*)d_in[2], (const float*)d_in[3]};
  const float* qf = (const float*)d_in[4];
  const float* qe = (const float*)d_in[5];
  const float* ca_wqkv = (const float*)d_in[6];
  const float* ca_bqkv = (const float*)d_in[7];
  const float* ca_wo = (const float*)d_in[8];
  const float* ca_bo = (const float*)d_in[9];
  const float* ca_ln_s = (const float*)d_in[10];
  const float* ca_ln_b = (const float*)d_in[11];
  const float* sa_wqkv = (const float*)d_in[12];
  const float* sa_bqkv = (const float*)d_in[13];
  const float* sa_wo = (const float*)d_in[14];
  const float* sa_bo = (const float*)d_in[15];
  const float* sa_ln_s = (const float*)d_in[16];
  const float* sa_ln_b = (const float*)d_in[17];
  const float* ffn_w1 = (const float*)d_in[18];
  const float* ffn_b1 = (const float*)d_in[19];
  const float* ffn_w2 = (const float*)d_in[20];
  const float* ffn_b2 = (const float*)d_in[21];
  const float* ffn_ln_s = (const float*)d_in[22];
  const float* ffn_ln_b = (const float*)d_in[23];
  const float* dec_ln_s = (const float*)d_in[24];
  const float* dec_ln_b = (const float*)d_in[25];
  const float* me_w1 = (const float*)d_in[26];
  const float* me_b1 = (const float*)d_in[27];
  const float* me_w2 = (const float*)d_in[28];
  const float* me_b2 = (const float*)d_in[29];
  const float* me_w3 = (const float*)d_in[30];
  const float* me_b3 = (const float*)d_in[31];
  const float* cls_w = (const float*)d_in[32];
  const float* cls_b = (const float*)d_in[33];

  float* out_logits = (float*)d_out;                       // [800,151]
  float* out_mask = (float*)d_out + (size_t)800 * C_;      // [800,12544] — also 'prev'

  float* ws = (float*)d_ws;
  float* q      = ws; ws += (size_t)800 * D_;
  float* qh     = ws; ws += (size_t)800 * D_;
  float* attn_o = ws; ws += (size_t)800 * D_;
  float* tmp    = ws; ws += (size_t)800 * D_;
  float* nq     = ws; ws += (size_t)800 * D_;
  float* me1    = ws; ws += (size_t)800 * D_;
  float* me2    = ws; ws += (size_t)800 * D_;
  float* me3    = ws; ws += (size_t)800 * D_;
  float* kh     = ws; ws += (size_t)B_ * PMAX_ * D_;
  float* vh     = ws; ws += (size_t)B_ * PMAX_ * D_;
  float* biasb  = ws; ws += (size_t)B_ * Q_ * PMAX_;
  float* ffnh   = ws; ws += (size_t)B_ * Q_ * F_;

  initq_kernel<<<800, 256, 0, stream>>>(qf, qe, q);

  const int Ps[3] = {196, 784, 3136};
  const int ohs[3] = {14, 28, 56};
  for (int i = 0; i < L_; ++i) {
    const int mi = i % 3, P = Ps[mi], oh = ohs[mi];
    const float* bias_p = nullptr;
    if (i > 0) {
      maskbias_kernel<<<800, 256, 0, stream>>>(out_mask, biasb, oh);
      bias_p = biasb;
    }
    // ---- cross-attention ----
    gemm(stream, q, ca_wqkv + ((size_t)i * 3 + 0) * 65536, ca_bqkv + (i * 3 + 0) * 256,
         qh, 800, 256, 256, 1, 0, 0, 0, false, false);
    gemm(stream, mem[mi], ca_wqkv + ((size_t)i * 3 + 1) * 65536, ca_bqkv + (i * 3 + 1) * 256,
         kh, P, 256, 256, B_, (long long)256 * P, 0, (long long)P * 256, true, false);
    gemm(stream, mem[mi], ca_wqkv + ((size_t)i * 3 + 2) * 65536, ca_bqkv + (i * 3 + 2) * 256,
         vh, P, 256, 256, B_, (long long)256 * P, 0, (long long)P * 256, true, false);
    attn_kernel<<<dim3(25, 8, 8), 256, (4 * P + 128) * 4, stream>>>(qh, kh, vh, bias_p, attn_o, P);
    gemm(stream, attn_o, ca_wo + (size_t)i * 65536, ca_bo + i * 256, tmp,
         800, 256, 256, 1, 0, 0, 0, false, false);
    ln_kernel<true><<<800, 256, 0, stream>>>(q, tmp, ca_ln_s + i * 256, ca_ln_b + i * 256, q);
    // ---- self-attention ----
    gemm(stream, q, sa_wqkv + ((size_t)i * 3 + 0) * 65536, sa_bqkv + (i * 3 + 0) * 256,
         qh, 800, 256, 256, 1, 0, 0, 0, false, false);
    gemm(stream, q, sa_wqkv + ((size_t)i * 3 + 1) * 65536, sa_bqkv + (i * 3 + 1) * 256,
         kh, 800, 256, 256, 1, 0, 0, 0, false, false);
    gemm(stream, q, sa_wqkv + ((size_t)i * 3 + 2) * 65536, sa_bqkv + (i * 3 + 2) * 256,
         vh, 800, 256, 256, 1, 0, 0, 0, false, false);
    attn_kernel<<<dim3(25, 8, 8), 256, (4 * 100 + 128) * 4, stream>>>(qh, kh, vh, nullptr, attn_o, 100);
    gemm(stream, attn_o, sa_wo + (size_t)i * 65536, sa_bo + i * 256, tmp,
         800, 256, 256, 1, 0, 0, 0, false, false);
    ln_kernel<true><<<800, 256, 0, stream>>>(q, tmp, sa_ln_s + i * 256, sa_ln_b + i * 256, q);
    // ---- FFN ----
    gemm(stream, q, ffn_w1 + (size_t)i * 256 * 2048, ffn_b1 + i * 2048, ffnh,
         800, 2048, 256, 1, 0, 0, 0, false, true);
    gemm(stream, ffnh, ffn_w2 + (size_t)i * 2048 * 256, ffn_b2 + i * 256, tmp,
         800, 256, 2048, 1, 0, 0, 0, false, false);
    ln_kernel<true><<<800, 256, 0, stream>>>(q, tmp, ffn_ln_s + i * 256, ffn_ln_b + i * 256, q);
    // ---- mask head ----
    ln_kernel<false><<<800, 256, 0, stream>>>(q, nullptr, dec_ln_s, dec_ln_b, nq);
    gemm(stream, nq, me_w1, me_b1, me1, 800, 256, 256, 1, 0, 0, 0, false, true);
    gemm(stream, me1, me_w2, me_b2, me2, 800, 256, 256, 1, 0, 0, 0, false, true);
    gemm(stream, me2, me_w3, me_b3, me3, 800, 256, 256, 1, 0, 0, 0, false, false);
    gemm(stream, me3, mask_features, nullptr, out_mask, 100, 12544, 256, B_,
         (long long)100 * 256, (long long)256 * 12544, (long long)100 * 12544, false, false);
  }
  // ---- classifier head (uses last layer's nq) ----
  gemm(stream, nq, cls_w, cls_b, out_logits, 800, C_, 256, 1, 0, 0, 0, false, false);
}

// Round 2
// 10176.139 us; speedup vs baseline: 1.4807x; 1.4807x over previous
//
#include <hip/hip_runtime.h>
#include <cmath>

#define B_ 8
#define Q_ 100
#define D_ 256
#define H_ 8
#define HD_ 32
#define L_ 9
#define F_ 2048
#define C_ 151
#define HM_ 112
#define PMAX_ 3136
#define QT_ 16
#define KT_ 128

// ---------------- block reductions (256 threads) ----------------
__device__ __forceinline__ float block_sum(float v, float* red) {
  int t = threadIdx.x;
  red[t] = v; __syncthreads();
  for (int s = 128; s > 0; s >>= 1) {
    if (t < s) red[t] += red[t + s];
    __syncthreads();
  }
  float r = red[0]; __syncthreads();
  return r;
}

// ---------------- init q = qf + qe broadcast over batch ----------------
__global__ __launch_bounds__(256) void initq_kernel(const float* __restrict__ qf,
                                                    const float* __restrict__ qe,
                                                    float* __restrict__ q) {
  int idx = blockIdx.x * 256 + threadIdx.x;     // 800*256 total
  int qd = idx % (Q_ * D_);
  q[idx] = qf[qd] + qe[qd];
}

// ---------------- generic fp32 GEMM: C = A@W (+bias)(+relu) ----------------
// A: [M,K] row-major (AT=false) or stored [K,M] (AT=true).
// W: [K,N] row-major, or (QKVW) chunked [N/256][K][256].
template <bool AT, bool RELU, bool QKVW>
__global__ __launch_bounds__(256) void gemm_kernel(
    const float* __restrict__ A, const float* __restrict__ W,
    const float* __restrict__ bias, float* __restrict__ C,
    int M, int N, int K, long long Abs, long long Wbs, long long Cbs, int ldc) {
  __shared__ float As[16][65];
  __shared__ float Ws[16][65];
  const int z = blockIdx.z;
  const float* Ab = A + (size_t)z * Abs;
  const float* Wb = W + (size_t)z * Wbs;
  float* Cb = C + (size_t)z * Cbs;
  const int n0 = blockIdx.x * 64, m0 = blockIdx.y * 64;
  const int t = threadIdx.x;
  const int tm = t >> 4, tn = t & 15;
  float acc[4][4] = {};
  for (int k0 = 0; k0 < K; k0 += 16) {
#pragma unroll
    for (int l = 0; l < 4; ++l) {
      int idx = t + l * 256;
      if (AT) {
        int ak = idx >> 6, am = idx & 63;
        int gm = m0 + am, gk = k0 + ak;
        As[ak][am] = (gm < M) ? Ab[(size_t)gk * M + gm] : 0.f;
      } else {
        int am = idx >> 4, ak = idx & 15;
        int gm = m0 + am, gk = k0 + ak;
        As[ak][am] = (gm < M) ? Ab[(size_t)gm * K + gk] : 0.f;
      }
      int wk = idx >> 6, wn = idx & 63;
      int gn = n0 + wn, gk2 = k0 + wk;
      float wv = 0.f;
      if (gn < N) {
        if (QKVW)
          wv = Wb[(size_t)(gn >> 8) * 65536 + (size_t)gk2 * 256 + (gn & 255)];
        else
          wv = Wb[(size_t)gk2 * N + gn];
      }
      Ws[wk][wn] = wv;
    }
    __syncthreads();
#pragma unroll
    for (int kk = 0; kk < 16; ++kk) {
      float a[4], b[4];
#pragma unroll
      for (int i = 0; i < 4; ++i) a[i] = As[kk][tm * 4 + i];
#pragma unroll
      for (int j = 0; j < 4; ++j) b[j] = Ws[kk][tn * 4 + j];
#pragma unroll
      for (int i = 0; i < 4; ++i)
#pragma unroll
        for (int j = 0; j < 4; ++j) acc[i][j] += a[i] * b[j];
    }
    __syncthreads();
  }
#pragma unroll
  for (int i = 0; i < 4; ++i) {
    int gm = m0 + tm * 4 + i;
    if (gm >= M) continue;
#pragma unroll
    for (int j = 0; j < 4; ++j) {
      int gn = n0 + tn * 4 + j;
      if (gn >= N) continue;
      float v = acc[i][j] + (bias ? bias[gn] : 0.f);
      if (RELU) v = fmaxf(v, 0.f);
      Cb[(size_t)gm * ldc + gn] = v;
    }
  }
}

// ---------------- fused residual + layernorm ----------------
template <bool RES>
__global__ __launch_bounds__(256) void ln_kernel(const float* __restrict__ x,
                                                 const float* __restrict__ r,
                                                 const float* __restrict__ s,
                                                 const float* __restrict__ b,
                                                 float* __restrict__ out) {
  __shared__ float red[256];
  size_t row = blockIdx.x;
  int t = threadIdx.x;
  float v = x[row * D_ + t];
  if (RES) v += r[row * D_ + t];
  float mean = block_sum(v, red) * (1.f / D_);
  float c = v - mean;
  float var = block_sum(c * c, red) * (1.f / D_);
  out[row * D_ + t] = c * rsqrtf(var + 1e-5f) * s[t] + b[t];
}

// ---------------- flash attention (fp32, hd=32) ----------------
// grid (ceil(Q/16), H, B), 256 threads. Thread t: q-row r=t&15, k-slice c16=t>>4.
// K/V tiles 128x32 staged in LDS (row stride 36: 16B-aligned rows, <=2-way bank alias).
template <bool BIAS>
__global__ __launch_bounds__(256) void fattn_kernel(
    const float* __restrict__ qb, int ldq,
    const float* __restrict__ kb, int ldk,
    const float* __restrict__ vb, int ldv,
    const float* __restrict__ bias,
    float* __restrict__ out, int P) {
  __shared__ float smem[2 * KT_ * 36];   // K,V tiles; reused for final O combine
  __shared__ float red[256];
  __shared__ float lsave[QT_];
  float* Kt = smem;
  float* Vt = smem + KT_ * 36;
  const int b = blockIdx.z, h = blockIdx.y, q0 = blockIdx.x * QT_;
  const int t = threadIdx.x;
  const int r = t & 15, c16 = t >> 4;
  const int qrow = q0 + r;
  const int qcl = (qrow < Q_) ? qrow : 0;
  float4 qreg[8];
  {
    const float4* qp = reinterpret_cast<const float4*>(qb + (size_t)(b * Q_ + qcl) * ldq + h * HD_);
#pragma unroll
    for (int e = 0; e < 8; ++e) qreg[e] = qp[e];
  }
  const float* biasrow = BIAS ? (bias + (size_t)(b * Q_ + qcl) * P) : nullptr;
  float m = -3.0e38f, l = 0.f;
  float O[32];
#pragma unroll
  for (int e = 0; e < 32; ++e) O[e] = 0.f;
  const float scale = 0.17677669529663687f;   // 1/sqrt(32)

  for (int k0 = 0; k0 < P; k0 += KT_) {
    // ---- stage K,V tiles (coalesced float4) ----
#pragma unroll
    for (int i = 0; i < 4; ++i) {
      int f = t + i * 256;               // 0..1023
      int row = f >> 3, c4 = (f & 7) * 4;
      int gk = k0 + row;
      float4 kvv = make_float4(0.f, 0.f, 0.f, 0.f);
      float4 vvv = kvv;
      if (gk < P) {
        kvv = *reinterpret_cast<const float4*>(kb + (size_t)(b * P + gk) * ldk + h * HD_ + c4);
        vvv = *reinterpret_cast<const float4*>(vb + (size_t)(b * P + gk) * ldv + h * HD_ + c4);
      }
      *reinterpret_cast<float4*>(&Kt[row * 36 + c4]) = kvv;
      *reinterpret_cast<float4*>(&Vt[row * 36 + c4]) = vvv;
    }
    __syncthreads();
    // ---- scores for this thread's 8 keys ----
    float p[8];
    float pmax = -3.0e38f;
#pragma unroll
    for (int j = 0; j < 8; ++j) {
      int kk = c16 + 16 * j;
      int gkk = k0 + kk;
      const float4* kp = reinterpret_cast<const float4*>(&Kt[kk * 36]);
      float s = 0.f;
#pragma unroll
      for (int e = 0; e < 8; ++e) {
        float4 kv4 = kp[e];
        s += qreg[e].x * kv4.x + qreg[e].y * kv4.y + qreg[e].z * kv4.z + qreg[e].w * kv4.w;
      }
      s *= scale;
      if (BIAS && gkk < P) s += biasrow[gkk];
      if (gkk >= P) s = -3.0e38f;
      p[j] = s;
      pmax = fmaxf(pmax, s);
    }
    // ---- row max across the 16 k-slices ----
    red[t] = pmax;
    __syncthreads();
#pragma unroll
    for (int s = 8; s > 0; s >>= 1) {
      if (c16 < s) red[t] = fmaxf(red[t], red[t + s * 16]);
      __syncthreads();
    }
    float mnew = fmaxf(m, red[r]);
    float corr = __expf(m - mnew);
    m = mnew;
    float lsum = 0.f;
#pragma unroll
    for (int j = 0; j < 8; ++j) {
      p[j] = __expf(p[j] - mnew);
      lsum += p[j];
    }
    l = l * corr + lsum;
#pragma unroll
    for (int e = 0; e < 32; ++e) O[e] *= corr;
    // ---- PV ----
#pragma unroll
    for (int j = 0; j < 8; ++j) {
      int kk = c16 + 16 * j;
      const float4* vp = reinterpret_cast<const float4*>(&Vt[kk * 36]);
      float pj = p[j];
#pragma unroll
      for (int e = 0; e < 8; ++e) {
        float4 vv = vp[e];
        O[e * 4 + 0] += pj * vv.x;
        O[e * 4 + 1] += pj * vv.y;
        O[e * 4 + 2] += pj * vv.z;
        O[e * 4 + 3] += pj * vv.w;
      }
    }
    __syncthreads();   // tile consumed; safe to restage
  }
  // ---- final combine: l then O across the 16 k-slices ----
  red[t] = l;
  __syncthreads();
#pragma unroll
  for (int s = 8; s > 0; s >>= 1) {
    if (c16 < s) red[t] += red[t + s * 16];
    __syncthreads();
  }
  if (t < QT_) lsave[t] = red[t];
  float* sc = smem;                      // 256*33 = 8448 <= 9216 floats
#pragma unroll
  for (int e = 0; e < 32; ++e) sc[t * 33 + e] = O[e];
  __syncthreads();
  for (int o = t; o < QT_ * 32; o += 256) {
    int ro = o >> 5, eo = o & 31;
    if (q0 + ro < Q_) {
      float sacc = 0.f;
#pragma unroll
      for (int c = 0; c < 16; ++c) sacc += sc[(c * 16 + ro) * 33 + eo];
      out[(size_t)(b * Q_ + q0 + ro) * D_ + h * HD_ + eo] = sacc / lsave[ro];
    }
  }
}

// ---------------- attention-bias from prev mask ----------------
__global__ __launch_bounds__(256) void maskbias_kernel(
    const float* __restrict__ prev,   // [B*Q, 112*112]
    float* __restrict__ bias,         // [B*Q, P]
    int oh) {                         // 14 / 28 / 56
  __shared__ float pm[HM_ * HM_];
  __shared__ float rbuf[PMAX_];
  __shared__ float red[256];
  const int row = blockIdx.x;         // b*Q + q
  const int t = threadIdx.x;
  const float* src = prev + (size_t)row * (HM_ * HM_);
  for (int i = t; i < HM_ * HM_; i += 256) pm[i] = src[i];
  __syncthreads();
  const int ratio = HM_ / oh;         // 8, 4, 2
  const int taps = 2 * ratio;
  const float invr = 1.f / (float)ratio;
  const int P = oh * oh;
  float nign = 0.f;
  for (int p = t; p < P; p += 256) {
    int oy = p / oh, ox = p - oy * oh;
    float sy = (oy + 0.5f) * ratio - 0.5f;
    float sx = (ox + 0.5f) * ratio - 0.5f;
    int y0 = (int)floorf(sy - ratio) + 1;
    int x0 = (int)floorf(sx - ratio) + 1;
    float wxs = 0.f;
    for (int si = 0; si < taps; ++si) {
      int x = x0 + si;
      if (x < 0 || x >= HM_) continue;
      wxs += 1.f - fabsf(sx - x) * invr;
    }
    float acc = 0.f, wys = 0.f;
    for (int ti = 0; ti < taps; ++ti) {
      int y = y0 + ti;
      if (y < 0 || y >= HM_) continue;
      float wy = 1.f - fabsf(sy - y) * invr;
      wys += wy;
      float ra = 0.f;
      const float* pr = pm + y * HM_;
      for (int si = 0; si < taps; ++si) {
        int x = x0 + si;
        if (x < 0 || x >= HM_) continue;
        float wx = 1.f - fabsf(sx - x) * invr;
        ra += wx * pr[x];
      }
      acc += wy * ra;
    }
    float rv = acc / (wys * wxs);
    rbuf[p] = rv;
    if (!(rv < 0.f)) nign += 1.f;
  }
  float tot = block_sum(nign, red);
  bool fully = (tot == 0.f);
  float* dst = bias + (size_t)row * P;
  for (int p = t; p < P; p += 256) {
    dst[p] = (!fully && rbuf[p] < 0.f) ? -1e9f : 0.f;
  }
}

// ---------------- host-side GEMM dispatch ----------------
static inline void gemm(hipStream_t st, const float* A, const float* W, const float* bias,
                        float* C, int M, int N, int K, int Z,
                        long long Abs, long long Wbs, long long Cbs, int ldc,
                        bool AT, bool relu, bool qkvw) {
  dim3 g((N + 63) / 64, (M + 63) / 64, Z);
  if (!AT && !relu && !qkvw)
    gemm_kernel<false, false, false><<<g, 256, 0, st>>>(A, W, bias, C, M, N, K, Abs, Wbs, Cbs, ldc);
  else if (!AT && relu && !qkvw)
    gemm_kernel<false, true, false><<<g, 256, 0, st>>>(A, W, bias, C, M, N, K, Abs, Wbs, Cbs, ldc);
  else if (AT && !relu && qkvw)
    gemm_kernel<true, false, true><<<g, 256, 0, st>>>(A, W, bias, C, M, N, K, Abs, Wbs, Cbs, ldc);
  else
    gemm_kernel<false, false, true><<<g, 256, 0, st>>>(A, W, bias, C, M, N, K, Abs, Wbs, Cbs, ldc);
}

extern "C" void kernel_launch(void* const* d_in, const int* in_sizes, int n_in,
                              void* d_out, int out_size, void* d_ws, size_t ws_size,
                              hipStream_t stream) {
  const float* mask_features = (const float*)d_in[0];
  const float* mem[3] = {(const float*)d_in[1], (const float*)d_in[2], (const float*)d_in[3]};
  const float* qf = (const float*)d_in[4];
  const float* qe = (const float*)d_in[5];
  const float* ca_wqkv = (const float*)d_in[6];
  const float* ca_bqkv = (const float*)d_in[7];
  const float* ca_wo = (const float*)d_in[8];
  const float* ca_bo = (const float*)d_in[9];
  const float* ca_ln_s = (const float*)d_in[10];
  const float* ca_ln_b = (const float*)d_in[11];
  const float* sa_wqkv = (const float*)d_in[12];
  const float* sa_bqkv = (const float*)d_in[13];
  const float* sa_wo = (const float*)d_in[14];
  const float* sa_bo = (const float*)d_in[15];
  const float* sa_ln_s = (const float*)d_in[16];
  const float* sa_ln_b = (const float*)d_in[17];
  const float* ffn_w1 = (const float*)d_in[18];
  const float* ffn_b1 = (const float*)d_in[19];
  const float* ffn_w2 = (const float*)d_in[20];
  const float* ffn_b2 = (const float*)d_in[21];
  const float* ffn_ln_s = (const float*)d_in[22];
  const float* ffn_ln_b = (const float*)d_in[23];
  const float* dec_ln_s = (const float*)d_in[24];
  const float* dec_ln_b = (const float*)d_in[25];
  const float* me_w1 = (const float*)d_in[26];
  const float* me_b1 = (const float*)d_in[27];
  const float* me_w2 = (const float*)d_in[28];
  const float* me_b2 = (const float*)d_in[29];
  const float* me_w3 = (const float*)d_in[30];
  const float* me_b3 = (const float*)d_in[31];
  const float* cls_w = (const float*)d_in[32];
  const float* cls_b = (const float*)d_in[33];

  float* out_logits = (float*)d_out;                       // [800,151]
  float* out_mask = (float*)d_out + (size_t)800 * C_;      // [800,12544] — also 'prev'

  float* ws = (float*)d_ws;
  float* q      = ws; ws += (size_t)800 * D_;
  float* qh     = ws; ws += (size_t)800 * D_;
  float* attn_o = ws; ws += (size_t)800 * D_;
  float* tmp    = ws; ws += (size_t)800 * D_;
  float* nq     = ws; ws += (size_t)800 * D_;
  float* me1    = ws; ws += (size_t)800 * D_;
  float* me2    = ws; ws += (size_t)800 * D_;
  float* me3    = ws; ws += (size_t)800 * D_;
  float* kvbuf  = ws; ws += (size_t)B_ * PMAX_ * 512;      // [B][P][512]: K | V
  float* qkvbuf = ws; ws += (size_t)800 * 768;             // [800][768]: Q | K | V
  float* biasb  = ws; ws += (size_t)B_ * Q_ * PMAX_;
  float* ffnh   = ws; ws += (size_t)B_ * Q_ * F_;

  initq_kernel<<<800, 256, 0, stream>>>(qf, qe, q);

  const int Ps[3] = {196, 784, 3136};
  const int ohs[3] = {14, 28, 56};
  const dim3 ag(7, 8, 8);   // ceil(100/16), H, B
  for (int i = 0; i < L_; ++i) {
    const int mi = i % 3, P = Ps[mi], oh = ohs[mi];
    if (i > 0) maskbias_kernel<<<800, 256, 0, stream>>>(out_mask, biasb, oh);
    // ---- cross-attention ----
    gemm(stream, q, ca_wqkv + ((size_t)i * 3 + 0) * 65536, ca_bqkv + (i * 3 + 0) * 256,
         qh, 800, 256, 256, 1, 0, 0, 0, 256, false, false, false);
    gemm(stream, mem[mi], ca_wqkv + ((size_t)i * 3 + 1) * 65536, ca_bqkv + (i * 3 + 1) * 256,
         kvbuf, P, 512, 256, B_, (long long)256 * P, 0, (long long)P * 512, 512, true, false, true);
    if (i > 0)
      fattn_kernel<true><<<ag, 256, 0, stream>>>(qh, 256, kvbuf, 512, kvbuf + 256, 512,
                                                 biasb, attn_o, P);
    else
      fattn_kernel<false><<<ag, 256, 0, stream>>>(qh, 256, kvbuf, 512, kvbuf + 256, 512,
                                                  nullptr, attn_o, P);
    gemm(stream, attn_o, ca_wo + (size_t)i * 65536, ca_bo + i * 256, tmp,
         800, 256, 256, 1, 0, 0, 0, 256, false, false, false);
    ln_kernel<true><<<800, 256, 0, stream>>>(q, tmp, ca_ln_s + i * 256, ca_ln_b + i * 256, q);
    // ---- self-attention (fused QKV) ----
    gemm(stream, q, sa_wqkv + (size_t)i * 3 * 65536, sa_bqkv + (size_t)i * 3 * 256,
         qkvbuf, 800, 768, 256, 1, 0, 0, 0, 768, false, false, true);
    fattn_kernel<false><<<ag, 256, 0, stream>>>(qkvbuf, 768, qkvbuf + 256, 768, qkvbuf + 512, 768,
                                                nullptr, attn_o, 100);
    gemm(stream, attn_o, sa_wo + (size_t)i * 65536, sa_bo + i * 256, tmp,
         800, 256, 256, 1, 0, 0, 0, 256, false, false, false);
    ln_kernel<true><<<800, 256, 0, stream>>>(q, tmp, sa_ln_s + i * 256, sa_ln_b + i * 256, q);
    // ---- FFN ----
    gemm(stream, q, ffn_w1 + (size_t)i * 256 * 2048, ffn_b1 + i * 2048, ffnh,
         800, 2048, 256, 1, 0, 0, 0, 2048, false, true, false);
    gemm(stream, ffnh, ffn_w2 + (size_t)i * 2048 * 256, ffn_b2 + i * 256, tmp,
         800, 256, 2048, 1, 0, 0, 0, 256, false, false, false);
    ln_kernel<true><<<800, 256, 0, stream>>>(q, tmp, ffn_ln_s + i * 256, ffn_ln_b + i * 256, q);
    // ---- mask head ----
    ln_kernel<false><<<800, 256, 0, stream>>>(q, nullptr, dec_ln_s, dec_ln_b, nq);
    gemm(stream, nq, me_w1, me_b1, me1, 800, 256, 256, 1, 0, 0, 0, 256, false, true, false);
    gemm(stream, me1, me_w2, me_b2, me2, 800, 256, 256, 1, 0, 0, 0, 256, false, true, false);
    gemm(stream, me2, me_w3, me_b3, me3, 800, 256, 256, 1, 0, 0, 0, 256, false, false, false);
    gemm(stream, me3, mask_features, nullptr, out_mask, 100, 12544, 256, B_,
         (long long)100 * 256, (long long)256 * 12544, (long long)100 * 12544, 12544,
         false, false, false);
  }
  // ---- classifier head (uses last layer's nq) ----
  gemm(stream, nq, cls_w, cls_b, out_logits, 800, C_, 256, 1, 0, 0, 0, C_, false, false, false);
}

// Round 3
// 4203.373 us; speedup vs baseline: 3.5847x; 2.4209x over previous
//
#include <hip/hip_runtime.h>
#include <cmath>

#define B_ 8
#define Q_ 100
#define D_ 256
#define H_ 8
#define HD_ 32
#define L_ 9
#define F_ 2048
#define C_ 151
#define HM_ 112
#define PMAX_ 3136
#define QT_ 16
#define KT_ 128

// MFMA A/B fragment k-layout: 1 => k = 4*(lane>>4) + e%4 + 16*(e/4)  (two 4-blocks)
//                             0 => k = 8*(lane>>4) + e                (contiguous 8)
#define KBLK4 1

typedef __attribute__((ext_vector_type(4))) short s4v;
typedef __attribute__((ext_vector_type(8))) short s8v;
typedef __attribute__((ext_vector_type(4))) float f4v;

__device__ __forceinline__ unsigned short f2bf(float x) {
  unsigned int u = __float_as_uint(x);
  return (unsigned short)((u + 0x7fffu + ((u >> 16) & 1u)) >> 16);
}
__device__ __forceinline__ float bf2f(unsigned short h) {
  return __uint_as_float(((unsigned int)h) << 16);
}
__device__ __forceinline__ void split2(float x, short& h, short& l) {
  unsigned short hb = f2bf(x);
  float r = x - bf2f(hb);
  h = (short)hb;
  l = (short)f2bf(r);
}

// ---------------- block reductions (256 threads) ----------------
__device__ __forceinline__ float block_sum(float v, float* red) {
  int t = threadIdx.x;
  red[t] = v; __syncthreads();
  for (int s = 128; s > 0; s >>= 1) {
    if (t < s) red[t] += red[t + s];
    __syncthreads();
  }
  float r = red[0]; __syncthreads();
  return r;
}

// ---------------- init q = qf + qe broadcast over batch ----------------
__global__ __launch_bounds__(256) void initq_kernel(const float* __restrict__ qf,
                                                    const float* __restrict__ qe,
                                                    float* __restrict__ q) {
  int idx = blockIdx.x * 256 + threadIdx.x;
  int qd = idx % (Q_ * D_);
  q[idx] = qf[qd] + qe[qd];
}

// ---------------- transpose-split: fp32 [K][N] -> bf16 [N][2K] = [Wh|Wl] ----------------
__global__ __launch_bounds__(256) void tsplit_kernel(
    const float* __restrict__ in, short* __restrict__ out,
    int K, int N, long long ibs, long long obs) {
  __shared__ float tile[32][33];
  const int z = blockIdx.z;
  const int nb = blockIdx.x * 32, kb = blockIdx.y * 32;
  const float* I = in + (size_t)z * ibs;
  short* O = out + (size_t)z * obs;
  const int t = threadIdx.x;
  {
    const int r = t >> 3, c = (t & 7) * 4;
    const int gk = kb + r;
#pragma unroll
    for (int j = 0; j < 4; ++j) {
      int gn = nb + c + j;
      tile[r][c + j] = (gk < K && gn < N) ? I[(size_t)gk * N + gn] : 0.f;
    }
  }
  __syncthreads();
  {
    const int nr = t >> 3, kc = (t & 7) * 4;
    const int gn = nb + nr;
    if (gn < N) {
#pragma unroll
      for (int j = 0; j < 4; ++j) {
        int gk = kb + kc + j;
        if (gk < K) {
          short h, l; split2(tile[kc + j][nr], h, l);
          O[(size_t)gn * 2 * K + gk] = h;
          O[(size_t)gn * 2 * K + K + gk] = l;
        }
      }
    }
  }
}

// ---------------- MFMA bf16x3 GEMM ----------------
// C[m,n] = sum_k A[m,k] W[k,n] (+bias)(+relu), fp32 in/out, bf16x3 split internally.
// AMODE: 0 = A fp32 [M][K] row-major, split in-kernel
//        1 = A pre-split bf16 [M][2K] ([Ah|Al])
// WMODE: 0 = W pre-split bf16 [N][2K] ([Wh|Wl], n-major)
//        1 = W fp32 [K][N] k-major, transpose-split in-kernel
// Requires N % 128 == 0, K % 32 == 0. Tile 64x128, 256 threads = 4 waves (2x2).
__device__ __forceinline__ s8v ldfrag(const short* p) {
#if KBLK4
  s4v lo = *(const s4v*)p;
  s4v hi = *(const s4v*)(p + 16);
  return __builtin_shufflevector(lo, hi, 0, 1, 2, 3, 4, 5, 6, 7);
#else
  s4v lo = *(const s4v*)p;
  s4v hi = *(const s4v*)(p + 4);
  return __builtin_shufflevector(lo, hi, 0, 1, 2, 3, 4, 5, 6, 7);
#endif
}

template <int AMODE, int WMODE, bool RELU>
__global__ __launch_bounds__(256) void mgemm_kernel(
    const void* __restrict__ Ap, const void* __restrict__ Wp,
    const float* __restrict__ bias, float* __restrict__ C,
    int M, int N, int K,
    long long Abs, long long Wbs, long long Cbs, int ldc) {
  __shared__ short Ah[64 * 36], Al[64 * 36], Wh[128 * 36], Wl[128 * 36];
  const int z = blockIdx.z;
  const int n0 = blockIdx.x * 128, m0 = blockIdx.y * 64;
  const int t = threadIdx.x;
  const int lane = t & 63;
  const int wave = t >> 6;
  const int wm = wave >> 1, wn = wave & 1;
  const int lr = lane & 15, lg = lane >> 4;
  f4v acc[2][4];
#pragma unroll
  for (int i = 0; i < 2; ++i)
#pragma unroll
    for (int j = 0; j < 4; ++j) acc[i][j] = (f4v){0.f, 0.f, 0.f, 0.f};

  const int arow = t >> 2;  // 0..63

  for (int k0 = 0; k0 < K; k0 += 32) {
    // ---- stage A (h,l) ----
    if (AMODE == 0) {
      const float* A = (const float*)Ap + (size_t)z * Abs;
      const int kc = (t & 3) * 8;
      float x[8];
      if (m0 + arow < M) {
        const float* ap = A + (size_t)(m0 + arow) * K + k0 + kc;
        *(f4v*)&x[0] = *(const f4v*)ap;
        *(f4v*)&x[4] = *(const f4v*)(ap + 4);
      } else {
#pragma unroll
        for (int e = 0; e < 8; ++e) x[e] = 0.f;
      }
      s4v h0, h1, l0, l1;
#pragma unroll
      for (int e = 0; e < 4; ++e) { short hh, ll; split2(x[e], hh, ll); h0[e] = hh; l0[e] = ll; }
#pragma unroll
      for (int e = 0; e < 4; ++e) { short hh, ll; split2(x[4 + e], hh, ll); h1[e] = hh; l1[e] = ll; }
      *(s4v*)&Ah[arow * 36 + kc] = h0; *(s4v*)&Ah[arow * 36 + kc + 4] = h1;
      *(s4v*)&Al[arow * 36 + kc] = l0; *(s4v*)&Al[arow * 36 + kc + 4] = l1;
    } else {
      const short* A2 = (const short*)Ap + (size_t)z * Abs;
      const int c = t & 3, sel = c >> 1, ko = (c & 1) * 16;
      s8v v0 = {0, 0, 0, 0, 0, 0, 0, 0}, v1 = {0, 0, 0, 0, 0, 0, 0, 0};
      if (m0 + arow < M) {
        const short* ap = A2 + (size_t)(m0 + arow) * (2 * K) + sel * K + k0 + ko;
        v0 = *(const s8v*)ap;
        v1 = *(const s8v*)(ap + 8);
      }
      short* dst = sel ? Al : Ah;
      *(s4v*)&dst[arow * 36 + ko] = __builtin_shufflevector(v0, v0, 0, 1, 2, 3);
      *(s4v*)&dst[arow * 36 + ko + 4] = __builtin_shufflevector(v0, v0, 4, 5, 6, 7);
      *(s4v*)&dst[arow * 36 + ko + 8] = __builtin_shufflevector(v1, v1, 0, 1, 2, 3);
      *(s4v*)&dst[arow * 36 + ko + 12] = __builtin_shufflevector(v1, v1, 4, 5, 6, 7);
    }
    // ---- stage W (h,l) ----
    if (WMODE == 0) {
      const short* W2 = (const short*)Wp + (size_t)z * Wbs;
      const int n = t >> 1, sel = t & 1;
      const short* wp = W2 + (size_t)(n0 + n) * (2 * K) + sel * K + k0;
      short* dst = sel ? Wl : Wh;
#pragma unroll
      for (int j = 0; j < 4; ++j) {
        s8v v = *(const s8v*)(wp + j * 8);
        *(s4v*)&dst[n * 36 + j * 8] = __builtin_shufflevector(v, v, 0, 1, 2, 3);
        *(s4v*)&dst[n * 36 + j * 8 + 4] = __builtin_shufflevector(v, v, 4, 5, 6, 7);
      }
    } else {
      const float* W = (const float*)Wp + (size_t)z * Wbs;
      const int kr = t >> 3, c0 = (t & 7) * 16;
      const float* wp = W + (size_t)(k0 + kr) * N + n0 + c0;
      float x[16];
#pragma unroll
      for (int j = 0; j < 4; ++j) *(f4v*)&x[j * 4] = *(const f4v*)(wp + j * 4);
#pragma unroll
      for (int j = 0; j < 16; ++j) {
        short hh, ll; split2(x[j], hh, ll);
        Wh[(c0 + j) * 36 + kr] = hh;
        Wl[(c0 + j) * 36 + kr] = ll;
      }
    }
    __syncthreads();
    // ---- compute: 24 MFMA ----
    s8v whf[4], wlf[4];
#pragma unroll
    for (int ni = 0; ni < 4; ++ni) {
      whf[ni] = ldfrag(&Wh[(wn * 64 + ni * 16 + lr) * 36 + 4 * lg]);
      wlf[ni] = ldfrag(&Wl[(wn * 64 + ni * 16 + lr) * 36 + 4 * lg]);
    }
#pragma unroll
    for (int mi = 0; mi < 2; ++mi) {
      s8v ah = ldfrag(&Ah[(wm * 32 + mi * 16 + lr) * 36 + 4 * lg]);
      s8v al = ldfrag(&Al[(wm * 32 + mi * 16 + lr) * 36 + 4 * lg]);
#pragma unroll
      for (int ni = 0; ni < 4; ++ni) {
        acc[mi][ni] = __builtin_amdgcn_mfma_f32_16x16x32_bf16(ah, whf[ni], acc[mi][ni], 0, 0, 0);
        acc[mi][ni] = __builtin_amdgcn_mfma_f32_16x16x32_bf16(al, whf[ni], acc[mi][ni], 0, 0, 0);
        acc[mi][ni] = __builtin_amdgcn_mfma_f32_16x16x32_bf16(ah, wlf[ni], acc[mi][ni], 0, 0, 0);
      }
    }
    __syncthreads();
  }
  // ---- epilogue: C/D layout col=lane&15, row=4*(lane>>4)+i (m89-verified) ----
  float* Cb = C + (size_t)z * Cbs;
#pragma unroll
  for (int mi = 0; mi < 2; ++mi) {
#pragma unroll
    for (int i = 0; i < 4; ++i) {
      int row = m0 + wm * 32 + mi * 16 + 4 * lg + i;
      if (row >= M) continue;
#pragma unroll
      for (int ni = 0; ni < 4; ++ni) {
        int col = n0 + wn * 64 + ni * 16 + lr;
        float v = acc[mi][ni][i] + (bias ? bias[col] : 0.f);
        if (RELU) v = fmaxf(v, 0.f);
        Cb[(size_t)row * ldc + col] = v;
      }
    }
  }
}

// ---------------- fp32 GEMM (cls head only, N=151) ----------------
__global__ __launch_bounds__(256) void gemm32_kernel(
    const float* __restrict__ A, const float* __restrict__ W,
    const float* __restrict__ bias, float* __restrict__ C,
    int M, int N, int K) {
  __shared__ float As[16][65];
  __shared__ float Ws[16][65];
  const int n0 = blockIdx.x * 64, m0 = blockIdx.y * 64;
  const int t = threadIdx.x;
  const int tm = t >> 4, tn = t & 15;
  float acc[4][4] = {};
  for (int k0 = 0; k0 < K; k0 += 16) {
#pragma unroll
    for (int l = 0; l < 4; ++l) {
      int idx = t + l * 256;
      int am = idx >> 4, ak = idx & 15;
      int gm = m0 + am, gk = k0 + ak;
      As[ak][am] = (gm < M) ? A[(size_t)gm * K + gk] : 0.f;
      int wk = idx >> 6, wn = idx & 63;
      int gn = n0 + wn, gk2 = k0 + wk;
      Ws[wk][wn] = (gn < N) ? W[(size_t)gk2 * N + gn] : 0.f;
    }
    __syncthreads();
#pragma unroll
    for (int kk = 0; kk < 16; ++kk) {
      float a[4], b[4];
#pragma unroll
      for (int i = 0; i < 4; ++i) a[i] = As[kk][tm * 4 + i];
#pragma unroll
      for (int j = 0; j < 4; ++j) b[j] = Ws[kk][tn * 4 + j];
#pragma unroll
      for (int i = 0; i < 4; ++i)
#pragma unroll
        for (int j = 0; j < 4; ++j) acc[i][j] += a[i] * b[j];
    }
    __syncthreads();
  }
#pragma unroll
  for (int i = 0; i < 4; ++i) {
    int gm = m0 + tm * 4 + i;
    if (gm >= M) continue;
#pragma unroll
    for (int j = 0; j < 4; ++j) {
      int gn = n0 + tn * 4 + j;
      if (gn >= N) continue;
      C[(size_t)gm * N + gn] = acc[i][j] + bias[gn];
    }
  }
}

// ---------------- fused residual + layernorm ----------------
template <bool RES>
__global__ __launch_bounds__(256) void ln_kernel(const float* __restrict__ x,
                                                 const float* __restrict__ r,
                                                 const float* __restrict__ s,
                                                 const float* __restrict__ b,
                                                 float* __restrict__ out) {
  __shared__ float red[256];
  size_t row = blockIdx.x;
  int t = threadIdx.x;
  float v = x[row * D_ + t];
  if (RES) v += r[row * D_ + t];
  float mean = block_sum(v, red) * (1.f / D_);
  float c = v - mean;
  float var = block_sum(c * c, red) * (1.f / D_);
  out[row * D_ + t] = c * rsqrtf(var + 1e-5f) * s[t] + b[t];
}

// ---------------- flash attention (fp32, hd=32) ----------------
template <bool BIAS>
__global__ __launch_bounds__(256) void fattn_kernel(
    const float* __restrict__ qb, int ldq,
    const float* __restrict__ kb, int ldk,
    const float* __restrict__ vb, int ldv,
    const float* __restrict__ bias,
    float* __restrict__ out, int P) {
  __shared__ float smem[2 * KT_ * 36];
  __shared__ float red[256];
  __shared__ float lsave[QT_];
  float* Kt = smem;
  float* Vt = smem + KT_ * 36;
  const int b = blockIdx.z, h = blockIdx.y, q0 = blockIdx.x * QT_;
  const int t = threadIdx.x;
  const int r = t & 15, c16 = t >> 4;
  const int qrow = q0 + r;
  const int qcl = (qrow < Q_) ? qrow : 0;
  float4 qreg[8];
  {
    const float4* qp = reinterpret_cast<const float4*>(qb + (size_t)(b * Q_ + qcl) * ldq + h * HD_);
#pragma unroll
    for (int e = 0; e < 8; ++e) qreg[e] = qp[e];
  }
  const float* biasrow = BIAS ? (bias + (size_t)(b * Q_ + qcl) * P) : nullptr;
  float m = -3.0e38f, l = 0.f;
  float O[32];
#pragma unroll
  for (int e = 0; e < 32; ++e) O[e] = 0.f;
  const float scale = 0.17677669529663687f;

  for (int k0 = 0; k0 < P; k0 += KT_) {
#pragma unroll
    for (int i = 0; i < 4; ++i) {
      int f = t + i * 256;
      int row = f >> 3, c4 = (f & 7) * 4;
      int gk = k0 + row;
      float4 kvv = make_float4(0.f, 0.f, 0.f, 0.f);
      float4 vvv = kvv;
      if (gk < P) {
        kvv = *reinterpret_cast<const float4*>(kb + (size_t)(b * P + gk) * ldk + h * HD_ + c4);
        vvv = *reinterpret_cast<const float4*>(vb + (size_t)(b * P + gk) * ldv + h * HD_ + c4);
      }
      *reinterpret_cast<float4*>(&Kt[row * 36 + c4]) = kvv;
      *reinterpret_cast<float4*>(&Vt[row * 36 + c4]) = vvv;
    }
    __syncthreads();
    float p[8];
    float pmax = -3.0e38f;
#pragma unroll
    for (int j = 0; j < 8; ++j) {
      int kk = c16 + 16 * j;
      int gkk = k0 + kk;
      const float4* kp = reinterpret_cast<const float4*>(&Kt[kk * 36]);
      float s = 0.f;
#pragma unroll
      for (int e = 0; e < 8; ++e) {
        float4 kv4 = kp[e];
        s += qreg[e].x * kv4.x + qreg[e].y * kv4.y + qreg[e].z * kv4.z + qreg[e].w * kv4.w;
      }
      s *= scale;
      if (BIAS && gkk < P) s += biasrow[gkk];
      if (gkk >= P) s = -3.0e38f;
      p[j] = s;
      pmax = fmaxf(pmax, s);
    }
    red[t] = pmax;
    __syncthreads();
#pragma unroll
    for (int s = 8; s > 0; s >>= 1) {
      if (c16 < s) red[t] = fmaxf(red[t], red[t + s * 16]);
      __syncthreads();
    }
    float mnew = fmaxf(m, red[r]);
    float corr = __expf(m - mnew);
    m = mnew;
    float lsum = 0.f;
#pragma unroll
    for (int j = 0; j < 8; ++j) {
      p[j] = __expf(p[j] - mnew);
      lsum += p[j];
    }
    l = l * corr + lsum;
#pragma unroll
    for (int e = 0; e < 32; ++e) O[e] *= corr;
#pragma unroll
    for (int j = 0; j < 8; ++j) {
      int kk = c16 + 16 * j;
      const float4* vp = reinterpret_cast<const float4*>(&Vt[kk * 36]);
      float pj = p[j];
#pragma unroll
      for (int e = 0; e < 8; ++e) {
        float4 vv = vp[e];
        O[e * 4 + 0] += pj * vv.x;
        O[e * 4 + 1] += pj * vv.y;
        O[e * 4 + 2] += pj * vv.z;
        O[e * 4 + 3] += pj * vv.w;
      }
    }
    __syncthreads();
  }
  red[t] = l;
  __syncthreads();
#pragma unroll
  for (int s = 8; s > 0; s >>= 1) {
    if (c16 < s) red[t] += red[t + s * 16];
    __syncthreads();
  }
  if (t < QT_) lsave[t] = red[t];
  float* sc = smem;
#pragma unroll
  for (int e = 0; e < 32; ++e) sc[t * 33 + e] = O[e];
  __syncthreads();
  for (int o = t; o < QT_ * 32; o += 256) {
    int ro = o >> 5, eo = o & 31;
    if (q0 + ro < Q_) {
      float sacc = 0.f;
#pragma unroll
      for (int c = 0; c < 16; ++c) sacc += sc[(c * 16 + ro) * 33 + eo];
      out[(size_t)(b * Q_ + q0 + ro) * D_ + h * HD_ + eo] = sacc / lsave[ro];
    }
  }
}

// ---------------- attention-bias from prev mask ----------------
__global__ __launch_bounds__(256) void maskbias_kernel(
    const float* __restrict__ prev,
    float* __restrict__ bias,
    int oh) {
  __shared__ float pm[HM_ * HM_];
  __shared__ float rbuf[PMAX_];
  __shared__ float red[256];
  const int row = blockIdx.x;
  const int t = threadIdx.x;
  const float* src = prev + (size_t)row * (HM_ * HM_);
  for (int i = t; i < HM_ * HM_; i += 256) pm[i] = src[i];
  __syncthreads();
  const int ratio = HM_ / oh;
  const int taps = 2 * ratio;
  const float invr = 1.f / (float)ratio;
  const int P = oh * oh;
  float nign = 0.f;
  for (int p = t; p < P; p += 256) {
    int oy = p / oh, ox = p - oy * oh;
    float sy = (oy + 0.5f) * ratio - 0.5f;
    float sx = (ox + 0.5f) * ratio - 0.5f;
    int y0 = (int)floorf(sy - ratio) + 1;
    int x0 = (int)floorf(sx - ratio) + 1;
    float wxs = 0.f;
    for (int si = 0; si < taps; ++si) {
      int x = x0 + si;
      if (x < 0 || x >= HM_) continue;
      wxs += 1.f - fabsf(sx - x) * invr;
    }
    float acc = 0.f, wys = 0.f;
    for (int ti = 0; ti < taps; ++ti) {
      int y = y0 + ti;
      if (y < 0 || y >= HM_) continue;
      float wy = 1.f - fabsf(sy - y) * invr;
      wys += wy;
      float ra = 0.f;
      const float* pr = pm + y * HM_;
      for (int si = 0; si < taps; ++si) {
        int x = x0 + si;
        if (x < 0 || x >= HM_) continue;
        float wx = 1.f - fabsf(sx - x) * invr;
        ra += wx * pr[x];
      }
      acc += wy * ra;
    }
    float rv = acc / (wys * wxs);
    rbuf[p] = rv;
    if (!(rv < 0.f)) nign += 1.f;
  }
  float tot = block_sum(nign, red);
  bool fully = (tot == 0.f);
  float* dst = bias + (size_t)row * P;
  for (int p = t; p < P; p += 256) {
    dst[p] = (!fully && rbuf[p] < 0.f) ? -1e9f : 0.f;
  }
}

// ---------------- host dispatch ----------------
static inline void mg(hipStream_t st, int amode, int wmode, bool relu,
                      const void* A, const void* W, const float* bias, float* C,
                      int M, int N, int K, int Z,
                      long long Abs, long long Wbs, long long Cbs, int ldc) {
  dim3 g(N / 128, (M + 63) / 64, Z);
  if (amode == 0 && wmode == 0 && !relu)
    mgemm_kernel<0, 0, false><<<g, 256, 0, st>>>(A, W, bias, C, M, N, K, Abs, Wbs, Cbs, ldc);
  else if (amode == 0 && wmode == 0 && relu)
    mgemm_kernel<0, 0, true><<<g, 256, 0, st>>>(A, W, bias, C, M, N, K, Abs, Wbs, Cbs, ldc);
  else if (amode == 1)
    mgemm_kernel<1, 0, false><<<g, 256, 0, st>>>(A, W, bias, C, M, N, K, Abs, Wbs, Cbs, ldc);
  else
    mgemm_kernel<0, 1, false><<<g, 256, 0, st>>>(A, W, bias, C, M, N, K, Abs, Wbs, Cbs, ldc);
}

extern "C" void kernel_launch(void* const* d_in, const int* in_sizes, int n_in,
                              void* d_out, int out_size, void* d_ws, size_t ws_size,
                              hipStream_t stream) {
  const float* mask_features = (const float*)d_in[0];
  const float* mem[3] = {(const float*)d_in[1], (const float*)d_in[2], (const float*)d_in[3]};
  const float* qf = (const float*)d_in[4];
  const float* qe = (const float*)d_in[5];
  const float* ca_wqkv = (const float*)d_in[6];
  const float* ca_bqkv = (const float*)d_in[7];
  const float* ca_wo = (const float*)d_in[8];
  const float* ca_bo = (const float*)d_in[9];
  const float* ca_ln_s = (const float*)d_in[10];
  const float* ca_ln_b = (const float*)d_in[11];
  const float* sa_wqkv = (const float*)d_in[12];
  const float* sa_bqkv = (const float*)d_in[13];
  const float* sa_wo = (const float*)d_in[14];
  const float* sa_bo = (const float*)d_in[15];
  const float* sa_ln_s = (const float*)d_in[16];
  const float* sa_ln_b = (const float*)d_in[17];
  const float* ffn_w1 = (const float*)d_in[18];
  const float* ffn_b1 = (const float*)d_in[19];
  const float* ffn_w2 = (const float*)d_in[20];
  const float* ffn_b2 = (const float*)d_in[21];
  const float* ffn_ln_s = (const float*)d_in[22];
  const float* ffn_ln_b = (const float*)d_in[23];
  const float* dec_ln_s = (const float*)d_in[24];
  const float* dec_ln_b = (const float*)d_in[25];
  const float* me_w1 = (const float*)d_in[26];
  const float* me_b1 = (const float*)d_in[27];
  const float* me_w2 = (const float*)d_in[28];
  const float* me_b2 = (const float*)d_in[29];
  const float* me_w3 = (const float*)d_in[30];
  const float* me_b3 = (const float*)d_in[31];
  const float* cls_w = (const float*)d_in[32];
  const float* cls_b = (const float*)d_in[33];

  float* out_logits = (float*)d_out;
  float* out_mask = (float*)d_out + (size_t)800 * C_;

  float* fws = (float*)d_ws;
  float* q      = fws; fws += (size_t)800 * D_;
  float* qh     = fws; fws += (size_t)800 * D_;
  float* attn_o = fws; fws += (size_t)800 * D_;
  float* tmp    = fws; fws += (size_t)800 * D_;
  float* nq     = fws; fws += (size_t)800 * D_;
  float* me1    = fws; fws += (size_t)800 * D_;
  float* me2    = fws; fws += (size_t)800 * D_;
  float* me3    = fws; fws += (size_t)800 * D_;
  float* kvbuf  = fws; fws += (size_t)B_ * PMAX_ * 512;
  float* qkvbuf = fws; fws += (size_t)800 * 768;
  float* biasb  = fws; fws += (size_t)B_ * Q_ * PMAX_;
  float* ffnh   = fws; fws += (size_t)B_ * Q_ * F_;

  short* sws = (short*)fws;
  short* W2ca  = sws; sws += (size_t)27 * 256 * 512;
  short* W2sa  = sws; sws += (size_t)27 * 256 * 512;
  short* W2cao = sws; sws += (size_t)9 * 256 * 512;
  short* W2sao = sws; sws += (size_t)9 * 256 * 512;
  short* W2f1  = sws; sws += (size_t)9 * 2048 * 512;
  short* W2f2  = sws; sws += (size_t)9 * 256 * 4096;
  short* W2me  = sws; sws += (size_t)3 * 256 * 512;
  short* mem2s = sws; sws += (size_t)B_ * 3136 * 512;
  short* mem1s = sws; sws += (size_t)B_ * 784 * 512;
  short* mem0s = sws; sws += (size_t)B_ * 196 * 512;
  short* memsp[3] = {mem0s, mem1s, mem2s};

  // ---- one-time (per call) weight / memory transpose-splits ----
  tsplit_kernel<<<dim3(8, 8, 27), 256, 0, stream>>>(ca_wqkv, W2ca, 256, 256, 65536, 131072);
  tsplit_kernel<<<dim3(8, 8, 27), 256, 0, stream>>>(sa_wqkv, W2sa, 256, 256, 65536, 131072);
  tsplit_kernel<<<dim3(8, 8, 9), 256, 0, stream>>>(ca_wo, W2cao, 256, 256, 65536, 131072);
  tsplit_kernel<<<dim3(8, 8, 9), 256, 0, stream>>>(sa_wo, W2sao, 256, 256, 65536, 131072);
  tsplit_kernel<<<dim3(64, 8, 9), 256, 0, stream>>>(ffn_w1, W2f1, 256, 2048, 524288, 1048576);
  tsplit_kernel<<<dim3(8, 64, 9), 256, 0, stream>>>(ffn_w2, W2f2, 2048, 256, 524288, 1048576);
  tsplit_kernel<<<dim3(8, 8, 1), 256, 0, stream>>>(me_w1, W2me, 256, 256, 0, 0);
  tsplit_kernel<<<dim3(8, 8, 1), 256, 0, stream>>>(me_w2, W2me + 131072, 256, 256, 0, 0);
  tsplit_kernel<<<dim3(8, 8, 1), 256, 0, stream>>>(me_w3, W2me + 262144, 256, 256, 0, 0);
  tsplit_kernel<<<dim3(7, 8, 8), 256, 0, stream>>>(mem[0], mem0s, 256, 196, 256 * 196, 196 * 512);
  tsplit_kernel<<<dim3(25, 8, 8), 256, 0, stream>>>(mem[1], mem1s, 256, 784, 256 * 784, 784 * 512);
  tsplit_kernel<<<dim3(98, 8, 8), 256, 0, stream>>>(mem[2], mem2s, 256, 3136, 256 * 3136, 3136 * 512);

  initq_kernel<<<800, 256, 0, stream>>>(qf, qe, q);

  const int Ps[3] = {196, 784, 3136};
  const int ohs[3] = {14, 28, 56};
  const dim3 ag(7, 8, 8);
  for (int i = 0; i < L_; ++i) {
    const int mi = i % 3, P = Ps[mi], oh = ohs[mi];
    if (i > 0) maskbias_kernel<<<800, 256, 0, stream>>>(out_mask, biasb, oh);
    // ---- cross-attention ----
    mg(stream, 0, 0, false, q, W2ca + (size_t)(i * 3) * 131072, ca_bqkv + i * 768, qh,
       800, 256, 256, 1, 0, 0, 0, 256);
    mg(stream, 1, 0, false, memsp[mi], W2ca + (size_t)(i * 3 + 1) * 131072,
       ca_bqkv + i * 768 + 256, kvbuf,
       P, 512, 256, B_, (long long)P * 512, 0, (long long)P * 512, 512);
    if (i > 0)
      fattn_kernel<true><<<ag, 256, 0, stream>>>(qh, 256, kvbuf, 512, kvbuf + 256, 512,
                                                 biasb, attn_o, P);
    else
      fattn_kernel<false><<<ag, 256, 0, stream>>>(qh, 256, kvbuf, 512, kvbuf + 256, 512,
                                                  nullptr, attn_o, P);
    mg(stream, 0, 0, false, attn_o, W2cao + (size_t)i * 131072, ca_bo + i * 256, tmp,
       800, 256, 256, 1, 0, 0, 0, 256);
    ln_kernel<true><<<800, 256, 0, stream>>>(q, tmp, ca_ln_s + i * 256, ca_ln_b + i * 256, q);
    // ---- self-attention (fused QKV) ----
    mg(stream, 0, 0, false, q, W2sa + (size_t)(i * 3) * 131072, sa_bqkv + i * 768, qkvbuf,
       800, 768, 256, 1, 0, 0, 0, 768);
    fattn_kernel<false><<<ag, 256, 0, stream>>>(qkvbuf, 768, qkvbuf + 256, 768, qkvbuf + 512, 768,
                                                nullptr, attn_o, 100);
    mg(stream, 0, 0, false, attn_o, W2sao + (size_t)i * 131072, sa_bo + i * 256, tmp,
       800, 256, 256, 1, 0, 0, 0, 256);
    ln_kernel<true><<<800, 256, 0, stream>>>(q, tmp, sa_ln_s + i * 256, sa_ln_b + i * 256, q);
    // ---- FFN ----
    mg(stream, 0, 0, true, q, W2f1 + (size_t)i * 1048576, ffn_b1 + i * 2048, ffnh,
       800, 2048, 256, 1, 0, 0, 0, 2048);
    mg(stream, 0, 0, false, ffnh, W2f2 + (size_t)i * 1048576, ffn_b2 + i * 256, tmp,
       800, 256, 2048, 1, 0, 0, 0, 256);
    ln_kernel<true><<<800, 256, 0, stream>>>(q, tmp, ffn_ln_s + i * 256, ffn_ln_b + i * 256, q);
    // ---- mask head ----
    ln_kernel<false><<<800, 256, 0, stream>>>(q, nullptr, dec_ln_s, dec_ln_b, nq);
    mg(stream, 0, 0, true, nq, W2me, me_b1, me1, 800, 256, 256, 1, 0, 0, 0, 256);
    mg(stream, 0, 0, true, me1, W2me + 131072, me_b2, me2, 800, 256, 256, 1, 0, 0, 0, 256);
    mg(stream, 0, 0, false, me2, W2me + 262144, me_b3, me3, 800, 256, 256, 1, 0, 0, 0, 256);
    mg(stream, 0, 1, false, me3, mask_features, nullptr, out_mask,
       100, 12544, 256, B_, (long long)100 * 256, (long long)256 * 12544,
       (long long)100 * 12544, 12544);
  }
  // ---- classifier head ----
  gemm32_kernel<<<dim3(3, 13, 1), 256, 0, stream>>>(nq, cls_w, cls_b, out_logits, 800, C_, 256);
}